// Round 1
// baseline (1424.447 us; speedup 1.0000x reference)
//
#include <hip/hip_runtime.h>
#include <math.h>

#define KD 128
#define NS 4096
#define NE 4096
#define NK 128
#define NNODE (NS + NE + NK)      // 8320
#define ESE 131072
#define EEK 16384
#define NCSR (2*ESE + 2*EEK)      // 294912
#define BQ 8192

__device__ __forceinline__ float lrelu_(float x){ return x >= 0.f ? x : 0.2f*x; }
__device__ __forceinline__ float elu_(float x){ return x > 0.f ? x : __expf(x) - 1.f; }
__device__ __forceinline__ float sigm_(float x){ return 1.f/(1.f + __expf(-x)); }

// ---------- gather initial embeddings into unified node table ----------
__global__ void k_gather(const float* __restrict__ Es, const float* __restrict__ Ee,
                         const float* __restrict__ Ek, const int* __restrict__ sid,
                         const int* __restrict__ eid, const int* __restrict__ kid,
                         float* __restrict__ e0) {
  int i = blockIdx.x, t = threadIdx.x;     // grid NNODE, block KD
  const float* src; int r;
  if (i < NS)            { src = Es; r = sid[i]; }
  else if (i < NS + NE)  { src = Ee; r = eid[i - NS]; }
  else                   { src = Ek; r = kid[i - NS - NE]; }
  e0[i*KD + t] = src[r*KD + t];
}

// ---------- CSR build: histogram over both directions of both relations ----------
__global__ void k_hist(const int* __restrict__ se_src, const int* __restrict__ se_dst,
                       const int* __restrict__ ek_src, const int* __restrict__ ek_dst,
                       int* __restrict__ cnt) {
  int i = blockIdx.x*blockDim.x + threadIdx.x;
  if (i < ESE) {
    atomicAdd(&cnt[se_src[i]], 1);
    atomicAdd(&cnt[NS + se_dst[i]], 1);
  }
  if (i < EEK) {
    atomicAdd(&cnt[NS + ek_src[i]], 1);
    atomicAdd(&cnt[NS + NE + ek_dst[i]], 1);
  }
}

// single-block exclusive scan of NNODE counts -> row_ptr[NNODE+1]
__global__ void k_scan(const int* __restrict__ cnt, int* __restrict__ row_ptr) {
  __shared__ int sums[1024];
  const int CH = (NNODE + 1023) / 1024;    // 9
  int t = threadIdx.x;
  int base = t * CH;
  int local[CH];
  int s = 0;
  for (int j = 0; j < CH; j++) {
    int v = (base + j < NNODE) ? cnt[base + j] : 0;
    local[j] = s; s += v;
  }
  sums[t] = s; __syncthreads();
  for (int off = 1; off < 1024; off <<= 1) {
    int v = (t >= off) ? sums[t - off] : 0;
    __syncthreads();
    sums[t] += v;
    __syncthreads();
  }
  int excl = (t == 0) ? 0 : sums[t - 1];
  for (int j = 0; j < CH; j++)
    if (base + j < NNODE) row_ptr[base + j] = excl + local[j];
  if (t == 1023) row_ptr[NNODE] = sums[1023];
}

__global__ void k_scatter(const int* __restrict__ se_src, const int* __restrict__ se_dst,
                          const int* __restrict__ ek_src, const int* __restrict__ ek_dst,
                          const int* __restrict__ row_ptr, int* __restrict__ fill,
                          int* __restrict__ col) {
  int i = blockIdx.x*blockDim.x + threadIdx.x;
  if (i < ESE) {
    int s = se_src[i], d = NS + se_dst[i];
    col[row_ptr[s] + atomicAdd(&fill[s], 1)] = d;
    col[row_ptr[d] + atomicAdd(&fill[d], 1)] = s;
  }
  if (i < EEK) {
    int s = NS + ek_src[i], d = NS + NE + ek_dst[i];
    col[row_ptr[s] + atomicAdd(&fill[s], 1)] = d;
    col[row_ptr[d] + atomicAdd(&fill[d], 1)] = s;
  }
}

// ---------- h = emb @ W, fused ss = h@a_s, sd = h@a_d ----------
__global__ void k_hgemm(const float* __restrict__ emb, const float* __restrict__ W,
                        const float* __restrict__ as_, const float* __restrict__ ad_,
                        float* __restrict__ h, float* __restrict__ ss, float* __restrict__ sd) {
  int row = blockIdx.x, t = threadIdx.x;   // grid NNODE, block KD
  __shared__ float er[KD];
  __shared__ float red[KD];
  er[t] = emb[row*KD + t];
  __syncthreads();
  float acc = 0.f;
  #pragma unroll 8
  for (int k = 0; k < KD; k++) acc += er[k] * W[k*KD + t];  // coalesced across t
  h[row*KD + t] = acc;
  red[t] = acc * as_[t]; __syncthreads();
  for (int o = 64; o > 0; o >>= 1) { if (t < o) red[t] += red[t + o]; __syncthreads(); }
  if (t == 0) ss[row] = red[0];
  __syncthreads();
  red[t] = acc * ad_[t]; __syncthreads();
  for (int o = 64; o > 0; o >>= 1) { if (t < o) red[t] += red[t + o]; __syncthreads(); }
  if (t == 0) sd[row] = red[0];
}

// ---------- segment-softmax aggregation: one wave per destination node ----------
__global__ void k_agg(const int* __restrict__ row_ptr, const int* __restrict__ col,
                      const float* __restrict__ h, const float* __restrict__ ss,
                      const float* __restrict__ sd, float* __restrict__ out) {
  int wave = (blockIdx.x*blockDim.x + threadIdx.x) >> 6;
  int lane = threadIdx.x & 63;
  if (wave >= NNODE) return;
  int e0 = row_ptr[wave], e1 = row_ptr[wave + 1];
  float sdv = sd[wave];
  float m = -INFINITY;
  for (int e = e0; e < e1; e++) {
    float s = lrelu_(ss[col[e]] + sdv);       // broadcast loads, all lanes same
    m = fmaxf(m, s);
  }
  float l = 0.f, a0 = 0.f, a1 = 0.f;
  for (int e = e0; e < e1; e++) {
    int o = col[e];
    float s = lrelu_(ss[o] + sdv);
    float p = __expf(s - m);
    l += p;
    float2 mv = *(const float2*)&h[o*KD + lane*2]; // coalesced 512B row
    a0 += p * mv.x; a1 += p * mv.y;
  }
  float inv = 1.f / (l + 1e-16f);
  a0 = elu_(a0 * inv); a1 = elu_(a1 * inv);
  *(float2*)&out[wave*KD + lane*2] = make_float2(a0, a1);
}

// ---------- 1/(||row||+1e-12), one wave per row ----------
__global__ void k_invnorm(const float* __restrict__ x, float* __restrict__ inv, int n) {
  int row = (blockIdx.x*blockDim.x + threadIdx.x) >> 6;
  int lane = threadIdx.x & 63;
  if (row >= n) return;
  float2 v = *(const float2*)&x[row*KD + lane*2];
  float s = v.x*v.x + v.y*v.y;
  for (int off = 32; off > 0; off >>= 1) s += __shfl_down(s, off);
  s = __shfl(s, 0);
  if (lane == 0) inv[row] = 1.f / (sqrtf(s) + 1e-12f);
}

// ---------- similarity GEMM with fused exp / rowsum / colsum / diag ----------
__global__ __launch_bounds__(256)
void k_sim(const float* __restrict__ A, const float* __restrict__ B,
           const float* __restrict__ invA, const float* __restrict__ invB,
           float* __restrict__ rowsum, float* __restrict__ colsum, float* __restrict__ diag) {
  __shared__ float As[64][33], Bs[64][33];
  __shared__ float red[64][17];
  int bi = blockIdx.x, bj = blockIdx.y, tid = threadIdx.x;
  int tx = tid % 16, ty = tid / 16;
  int i0 = bi*64, j0 = bj*64;
  float acc[4][4] = {};
  for (int kc = 0; kc < KD; kc += 32) {
    for (int l = tid; l < 64*32; l += 256) {
      int r = l >> 5, c = l & 31;
      As[r][c] = A[(i0 + r)*KD + kc + c];
      Bs[r][c] = B[(j0 + r)*KD + kc + c];
    }
    __syncthreads();
    #pragma unroll
    for (int k = 0; k < 32; k++) {
      float a[4], b[4];
      #pragma unroll
      for (int u = 0; u < 4; u++) a[u] = As[ty*4 + u][k];
      #pragma unroll
      for (int v = 0; v < 4; v++) b[v] = Bs[tx*4 + v][k];
      #pragma unroll
      for (int u = 0; u < 4; u++)
        #pragma unroll
        for (int v = 0; v < 4; v++) acc[u][v] += a[u]*b[v];
    }
    __syncthreads();
  }
  float ia[4], ib[4], rsum[4] = {0,0,0,0}, csum[4] = {0,0,0,0};
  for (int u = 0; u < 4; u++) ia[u] = invA[i0 + ty*4 + u];
  for (int v = 0; v < 4; v++) ib[v] = invB[j0 + tx*4 + v];
  for (int u = 0; u < 4; u++)
    for (int v = 0; v < 4; v++) {
      float sim2 = acc[u][v] * ia[u] * ib[v] * 2.0f;   // sim / tau, tau=0.5
      int gi = i0 + ty*4 + u, gj = j0 + tx*4 + v;
      if (gi == gj) diag[gi] = sim2;
      float e = __expf(sim2);
      rsum[u] += e; csum[v] += e;
    }
  for (int u = 0; u < 4; u++) red[ty*4 + u][tx] = rsum[u];
  __syncthreads();
  if (tid < 64) {
    float s = 0; for (int x = 0; x < 16; x++) s += red[tid][x];
    atomicAdd(&rowsum[i0 + tid], s);
  }
  __syncthreads();
  for (int v = 0; v < 4; v++) red[tx*4 + v][ty] = csum[v];
  __syncthreads();
  if (tid < 64) {
    float s = 0; for (int x = 0; x < 16; x++) s += red[tid][x];
    atomicAdd(&colsum[j0 + tid], s);
  }
}

// loss += alpha/NS * sum_i [ (log rowsum_i - diag_i) + (log colsum_i - diag_i) ]
__global__ void k_loss(const float* __restrict__ rowsum, const float* __restrict__ colsum,
                       const float* __restrict__ diag, float alpha, float* __restrict__ loss) {
  __shared__ float red[256];
  int i = blockIdx.x*blockDim.x + threadIdx.x;
  float v = 0.f;
  if (i < NS) v = (logf(rowsum[i]) - diag[i]) + (logf(colsum[i]) - diag[i]);
  red[threadIdx.x] = v; __syncthreads();
  for (int off = 128; off > 0; off >>= 1) {
    if (threadIdx.x < off) red[threadIdx.x] += red[threadIdx.x + off];
    __syncthreads();
  }
  if (threadIdx.x == 0) atomicAdd(loss, alpha * red[0] / (float)NS);
}

// ---------- prediction head, fused; one block per batch element ----------
__global__ void k_head(const float* __restrict__ emain, const int* __restrict__ stu_index,
                       const int* __restrict__ exer_index,
                       const float* __restrict__ pW1, const float* __restrict__ pW2,
                       const float* __restrict__ pW3, const float* __restrict__ pb3,
                       const float* __restrict__ kn_r, float* __restrict__ out) {
  int b = blockIdx.x, t = threadIdx.x;  // grid BQ, block KD
  __shared__ float bs[KD], be[KD], pd[KD], r1[KD], r2[KD];
  int si = stu_index[b], ei = exer_index[b];
  bs[t] = emain[si*KD + t];
  be[t] = emain[(NS + ei)*KD + t];
  __syncthreads();
  float acc1 = 0.f, acc2 = 0.f;
  #pragma unroll 8
  for (int k = 0; k < KD; k++) { acc1 += bs[k]*pW1[t*KD + k]; acc2 += be[k]*pW2[t*KD + k]; }
  pd[t] = sigm_(acc1) - sigm_(acc2);
  __syncthreads();
  float acc3 = 0.f;
  #pragma unroll 8
  for (int k = 0; k < KD; k++) acc3 += pd[k]*pW3[t*KD + k];
  float o = sigm_(acc3 + pb3[t]);
  float kr = kn_r[b*KD + t];
  r1[t] = o*kr; r2[t] = kr; __syncthreads();
  for (int off = 64; off > 0; off >>= 1) {
    if (t < off) { r1[t] += r1[t + off]; r2[t] += r2[t + off]; }
    __syncthreads();
  }
  if (t == 0) out[b] = r1[0] / r2[0];
}

__global__ void k_copy1(const float* __restrict__ src, float* __restrict__ dst) { dst[0] = src[0]; }

extern "C" void kernel_launch(void* const* d_in, const int* in_sizes, int n_in,
                              void* d_out, int out_size, void* d_ws, size_t ws_size,
                              hipStream_t stream) {
  const float* E_stu  = (const float*)d_in[0];
  const float* E_exer = (const float*)d_in[1];
  const float* E_k    = (const float*)d_in[2];
  const float* W1  = (const float*)d_in[3];
  const float* a1s = (const float*)d_in[4];
  const float* a1d = (const float*)d_in[5];
  const float* W2  = (const float*)d_in[6];
  const float* a2s = (const float*)d_in[7];
  const float* a2d = (const float*)d_in[8];
  const float* pW1 = (const float*)d_in[9];
  const float* pW2 = (const float*)d_in[10];
  const float* pW3 = (const float*)d_in[11];
  const float* pb3 = (const float*)d_in[12];
  const float* kn_r = (const float*)d_in[13];
  const int* stu_ids  = (const int*)d_in[14];
  const int* exer_ids = (const int*)d_in[15];
  const int* k_ids    = (const int*)d_in[16];
  const int* se_src[3] = {(const int*)d_in[17], (const int*)d_in[21], (const int*)d_in[25]};
  const int* se_dst[3] = {(const int*)d_in[18], (const int*)d_in[22], (const int*)d_in[26]};
  const int* ek_src[3] = {(const int*)d_in[19], (const int*)d_in[23], (const int*)d_in[27]};
  const int* ek_dst[3] = {(const int*)d_in[20], (const int*)d_in[24], (const int*)d_in[28]};
  const int* stu_index  = (const int*)d_in[29];
  const int* exer_index = (const int*)d_in[30];
  float* out = (float*)d_out;  // [0..8191] = predictions, [8192] = closs

  // ---- workspace carve (~30 MB total) ----
  char* p = (char*)d_ws;
  auto carve = [&](size_t bytes) -> char* {
    char* r = p; p += (bytes + 255) & ~(size_t)255; return r;
  };
  float* e0    = (float*)carve((size_t)NNODE*KD*4);
  float* etmp  = (float*)carve((size_t)NNODE*KD*4);
  float* h     = (float*)carve((size_t)NNODE*KD*4);
  float* ss    = (float*)carve(NNODE*4);
  float* sd    = (float*)carve(NNODE*4);
  float* eout[3];
  for (int g = 0; g < 3; g++) eout[g] = (float*)carve((size_t)NNODE*KD*4);
  int* cnt_all = (int*)carve((size_t)3*NNODE*4);          // counts, then reused as fill
  int* row_ptr[3]; int* col[3];
  for (int g = 0; g < 3; g++) row_ptr[g] = (int*)carve((NNODE+1)*4);
  for (int g = 0; g < 3; g++) col[g]     = (int*)carve((size_t)NCSR*4);
  float* inv1 = (float*)carve((NS+NE)*4);
  float* inv2 = (float*)carve((NS+NE)*4);
  float* zbuf = (float*)carve((4*NS + 64)*4);             // rs_s, cs_s, rs_e, cs_e, loss (zeroed)
  float* rs_s = zbuf, *cs_s = zbuf + NS, *rs_e = zbuf + 2*NS, *cs_e = zbuf + 3*NS;
  float* lossbuf = zbuf + 4*NS;
  float* dg_s = (float*)carve(NS*4);
  float* dg_e = (float*)carve(NS*4);

  // ---- zero init (ws is poisoned 0xAA every launch) ----
  hipMemsetAsync(cnt_all, 0, (size_t)3*NNODE*4, stream);
  hipMemsetAsync(zbuf, 0, (4*NS + 64)*4, stream);

  // ---- gather e0 ----
  k_gather<<<NNODE, KD, 0, stream>>>(E_stu, E_exer, E_k, stu_ids, exer_ids, k_ids, e0);

  // ---- CSR build for 3 graphs ----
  int hgrid = (ESE + 255) / 256;
  for (int g = 0; g < 3; g++)
    k_hist<<<hgrid, 256, 0, stream>>>(se_src[g], se_dst[g], ek_src[g], ek_dst[g], cnt_all + g*NNODE);
  for (int g = 0; g < 3; g++)
    k_scan<<<1, 1024, 0, stream>>>(cnt_all + g*NNODE, row_ptr[g]);
  hipMemsetAsync(cnt_all, 0, (size_t)3*NNODE*4, stream);   // reuse as fill
  for (int g = 0; g < 3; g++)
    k_scatter<<<hgrid, 256, 0, stream>>>(se_src[g], se_dst[g], ek_src[g], ek_dst[g],
                                         row_ptr[g], cnt_all + g*NNODE, col[g]);

  // ---- 3 graphs x 2 GAT layers ----
  int agrid = (NNODE*64 + 255) / 256;
  for (int g = 0; g < 3; g++) {
    k_hgemm<<<NNODE, KD, 0, stream>>>(e0, W1, a1s, a1d, h, ss, sd);
    k_agg<<<agrid, 256, 0, stream>>>(row_ptr[g], col[g], h, ss, sd, etmp);
    k_hgemm<<<NNODE, KD, 0, stream>>>(etmp, W2, a2s, a2d, h, ss, sd);
    k_agg<<<agrid, 256, 0, stream>>>(row_ptr[g], col[g], h, ss, sd, eout[g]);
  }

  // ---- contrastive loss between v1 (eout[1]) and v2 (eout[2]) ----
  int ngrid = ((NS+NE)*64 + 255) / 256;
  k_invnorm<<<ngrid, 256, 0, stream>>>(eout[1], inv1, NS + NE);
  k_invnorm<<<ngrid, 256, 0, stream>>>(eout[2], inv2, NS + NE);
  dim3 sgrid(64, 64);
  k_sim<<<sgrid, 256, 0, stream>>>(eout[1],            eout[2],            inv1,      inv2,      rs_s, cs_s, dg_s);
  k_sim<<<sgrid, 256, 0, stream>>>(eout[1] + NS*KD,    eout[2] + NS*KD,    inv1 + NS, inv2 + NS, rs_e, cs_e, dg_e);
  k_loss<<<16, 256, 0, stream>>>(rs_s, cs_s, dg_s, 0.1f, lossbuf);
  k_loss<<<16, 256, 0, stream>>>(rs_e, cs_e, dg_e, 0.1f, lossbuf);

  // ---- prediction head on main (eout[0]) ----
  k_head<<<BQ, KD, 0, stream>>>(eout[0], stu_index, exer_index, pW1, pW2, pW3, pb3, kn_r, out);
  k_copy1<<<1, 1, 0, stream>>>(lossbuf, out + BQ);
}

// Round 2
// 677.714 us; speedup vs baseline: 2.1018x; 2.1018x over previous
//
#include <hip/hip_runtime.h>
#include <math.h>

#define KD 128
#define NS 4096
#define NE 4096
#define NK 128
#define NNODE (NS + NE + NK)      // 8320
#define ESE 131072
#define EEK 16384
#define NCSR (2*ESE + 2*EEK)      // 294912
#define BQ 8192
#define RP (NNODE + 1)

__device__ __forceinline__ float lrelu_(float x){ return x >= 0.f ? x : 0.2f*x; }
__device__ __forceinline__ float elu_(float x){ return x > 0.f ? x : __expf(x) - 1.f; }
__device__ __forceinline__ float sigm_(float x){ return 1.f/(1.f + __expf(-x)); }

struct EdgePtrs { const int* s_src[3]; const int* s_dst[3]; const int* e_src[3]; const int* e_dst[3]; };

// ---------- gather initial embeddings into unified node table ----------
__global__ void k_gather(const float* __restrict__ Es, const float* __restrict__ Ee,
                         const float* __restrict__ Ek, const int* __restrict__ sid,
                         const int* __restrict__ eid, const int* __restrict__ kid,
                         float* __restrict__ e0) {
  int i = blockIdx.x, t = threadIdx.x;     // grid NNODE, block KD
  const float* src; int r;
  if (i < NS)            { src = Es; r = sid[i]; }
  else if (i < NS + NE)  { src = Ee; r = eid[i - NS]; }
  else                   { src = Ek; r = kid[i - NS - NE]; }
  e0[(size_t)i*KD + t] = src[(size_t)r*KD + t];
}

// ---------- CSR build (all 3 graphs batched via blockIdx.y) ----------
__global__ void k_hist(EdgePtrs ep, int* __restrict__ cnt_all) {
  int g = blockIdx.y;
  int i = blockIdx.x*256 + threadIdx.x;
  int* cnt = cnt_all + g*NNODE;
  if (i < ESE) {
    atomicAdd(&cnt[ep.s_src[g][i]], 1);
    atomicAdd(&cnt[NS + ep.s_dst[g][i]], 1);
  }
  if (i < EEK) {
    atomicAdd(&cnt[NS + ep.e_src[g][i]], 1);
    atomicAdd(&cnt[NS + NE + ep.e_dst[g][i]], 1);
  }
}

__global__ void k_scan(const int* __restrict__ cnt_all, int* __restrict__ rp_all) {
  __shared__ int sums[1024];
  const int CH = (NNODE + 1023) / 1024;    // 9
  int g = blockIdx.x;
  const int* cnt = cnt_all + g*NNODE;
  int* row_ptr = rp_all + g*RP;
  int t = threadIdx.x;
  int base = t * CH;
  int local[CH];
  int s = 0;
  for (int j = 0; j < CH; j++) {
    int v = (base + j < NNODE) ? cnt[base + j] : 0;
    local[j] = s; s += v;
  }
  sums[t] = s; __syncthreads();
  for (int off = 1; off < 1024; off <<= 1) {
    int v = (t >= off) ? sums[t - off] : 0;
    __syncthreads();
    sums[t] += v;
    __syncthreads();
  }
  int excl = (t == 0) ? 0 : sums[t - 1];
  for (int j = 0; j < CH; j++)
    if (base + j < NNODE) row_ptr[base + j] = excl + local[j];
  if (t == 1023) row_ptr[NNODE] = sums[1023];
}

__global__ void k_scatter(EdgePtrs ep, const int* __restrict__ rp_all,
                          int* __restrict__ fill_all, int* __restrict__ col_all) {
  int g = blockIdx.y;
  int i = blockIdx.x*256 + threadIdx.x;
  const int* row_ptr = rp_all + g*RP;
  int* fill = fill_all + g*NNODE;
  int* col = col_all + (size_t)g*NCSR;
  if (i < ESE) {
    int s = ep.s_src[g][i], d = NS + ep.s_dst[g][i];
    col[row_ptr[s] + atomicAdd(&fill[s], 1)] = d;
    col[row_ptr[d] + atomicAdd(&fill[d], 1)] = s;
  }
  if (i < EEK) {
    int s = NS + ep.e_src[g][i], d = NS + NE + ep.e_dst[g][i];
    col[row_ptr[s] + atomicAdd(&fill[s], 1)] = d;
    col[row_ptr[d] + atomicAdd(&fill[d], 1)] = s;
  }
}

// ---------- transpose the 3 head weight matrices ----------
__global__ void k_tr(const float* __restrict__ pW1, const float* __restrict__ pW2,
                     const float* __restrict__ pW3, float* __restrict__ T) {
  __shared__ float tile[32][33];
  int m = blockIdx.z;
  const float* src = m == 0 ? pW1 : (m == 1 ? pW2 : pW3);
  float* dst = T + m*KD*KD;
  int bx = blockIdx.x*32, by = blockIdx.y*32;
  int tx = threadIdx.x, ty = threadIdx.y;   // block (32,8)
  for (int j = 0; j < 32; j += 8)
    tile[ty + j][tx] = src[(by + ty + j)*KD + bx + tx];
  __syncthreads();
  for (int j = 0; j < 32; j += 8)
    dst[(bx + ty + j)*KD + by + tx] = tile[tx][ty + j];
}

// ---------- register-blocked node GEMM: out[i][:] = act(in[i][:] @ Wm) ----------
// 32 rows/block, 256 threads; wave w owns rows w*8..w*8+7, lane c handles cols c, c+64.
// MODE 0: out = in@Wa (no act) + fused ss/sd (v1=a_s, v2=a_d)
// MODE 1: out = sigm(in@W), W = (blockIdx < grid/2 ? Wa : Wb)   (P|D batched)
// MODE 2: head: o = sigm(in@Wa + v1[bias]); out[row] = sum(o*v2[row,:])/sum(v2[row,:])
template<int MODE>
__global__ __launch_bounds__(256)
void k_ngemm(const float* __restrict__ in, const float* __restrict__ Wa,
             const float* __restrict__ Wb,
             const float* __restrict__ v1, const float* __restrict__ v2,
             float* __restrict__ out, float* __restrict__ ss, float* __restrict__ sd,
             int nrows) {
  __shared__ float ers[32][KD];
  int t = threadIdx.x;
  int row0 = blockIdx.x * 32;
  const float* Wm = (MODE == 1 && blockIdx.x >= (gridDim.x >> 1)) ? Wb : Wa;
  for (int i = t; i < 32*KD; i += 256) {
    int r = i >> 7, k = i & 127;
    int gr = row0 + r;
    ers[r][k] = (gr < nrows) ? in[(size_t)gr*KD + k] : 0.f;
  }
  __syncthreads();
  int w = t >> 6, c = t & 63;
  float acc0[8] = {0,0,0,0,0,0,0,0}, acc1[8] = {0,0,0,0,0,0,0,0};
  #pragma unroll 2
  for (int kc = 0; kc < KD; kc += 4) {
    float wa[4], wb[4];
    #pragma unroll
    for (int j = 0; j < 4; j++) {
      wa[j] = Wm[(kc + j)*KD + c];
      wb[j] = Wm[(kc + j)*KD + c + 64];
    }
    #pragma unroll
    for (int r = 0; r < 8; r++) {
      float4 e = *(const float4*)&ers[w*8 + r][kc];   // wave-uniform broadcast read
      acc0[r] += e.x*wa[0] + e.y*wa[1] + e.z*wa[2] + e.w*wa[3];
      acc1[r] += e.x*wb[0] + e.y*wb[1] + e.z*wb[2] + e.w*wb[3];
    }
  }
  if (MODE == 0) {
    float as1 = v1[c], as2 = v1[c + 64], ad1 = v2[c], ad2 = v2[c + 64];
    #pragma unroll
    for (int r = 0; r < 8; r++) {
      int gr = row0 + w*8 + r;
      if (gr < nrows) {
        out[(size_t)gr*KD + c] = acc0[r];
        out[(size_t)gr*KD + c + 64] = acc1[r];
      }
      float s = acc0[r]*as1 + acc1[r]*as2;
      float d = acc0[r]*ad1 + acc1[r]*ad2;
      #pragma unroll
      for (int off = 32; off; off >>= 1) { s += __shfl_xor(s, off); d += __shfl_xor(d, off); }
      if (c == 0 && gr < nrows) { ss[gr] = s; sd[gr] = d; }
    }
  } else if (MODE == 1) {
    #pragma unroll
    for (int r = 0; r < 8; r++) {
      int gr = row0 + w*8 + r;
      if (gr < nrows) {
        out[(size_t)gr*KD + c] = sigm_(acc0[r]);
        out[(size_t)gr*KD + c + 64] = sigm_(acc1[r]);
      }
    }
  } else {
    float b1 = v1[c], b2 = v1[c + 64];
    #pragma unroll
    for (int r = 0; r < 8; r++) {
      int gr = row0 + w*8 + r;
      if (gr < nrows) {
        float kr1 = v2[(size_t)gr*KD + c], kr2 = v2[(size_t)gr*KD + c + 64];
        float o1 = sigm_(acc0[r] + b1), o2 = sigm_(acc1[r] + b2);
        float num = o1*kr1 + o2*kr2, den = kr1 + kr2;
        #pragma unroll
        for (int off = 32; off; off >>= 1) { num += __shfl_xor(num, off); den += __shfl_xor(den, off); }
        if (c == 0) out[gr] = num/den;
      }
    }
  }
}

// ---------- segment-softmax aggregation, 3 graphs batched; one wave/node ----------
__global__ void k_agg(const int* __restrict__ rp_all, const int* __restrict__ col_all,
                      const float* __restrict__ h, const float* __restrict__ ss,
                      const float* __restrict__ sd, float* __restrict__ out,
                      int shared_h) {
  int gw = blockIdx.x*4 + (threadIdx.x >> 6);
  int lane = threadIdx.x & 63;
  if (gw >= 3*NNODE) return;
  int g = gw / NNODE;
  int node = gw - g*NNODE;
  const int* rp = rp_all + g*RP;
  const int* cl = col_all + (size_t)g*NCSR;
  const float* hg  = shared_h ? h  : h  + (size_t)g*NNODE*KD;
  const float* ssg = shared_h ? ss : ss + g*NNODE;
  const float* sdg = shared_h ? sd : sd + g*NNODE;
  int e0 = rp[node], e1 = rp[node + 1];
  float sdv = sdg[node];
  // lane-parallel max
  float m = -INFINITY;
  for (int e = e0 + lane; e < e1; e += 64)
    m = fmaxf(m, lrelu_(ssg[cl[e]] + sdv));
  #pragma unroll
  for (int off = 32; off; off >>= 1) m = fmaxf(m, __shfl_xor(m, off));
  // lane-parallel exp + shuffle-broadcast row accumulation
  float l = 0.f, a0 = 0.f, a1 = 0.f;
  for (int base = e0; base < e1; base += 64) {
    int e = base + lane;
    float p = 0.f; int o = 0;
    if (e < e1) { o = cl[e]; p = __expf(lrelu_(ssg[o] + sdv) - m); }
    l += p;
    int cnt = min(64, e1 - base);
    for (int j = 0; j < cnt; j++) {
      float pj = __shfl(p, j);
      int oj = __shfl(o, j);
      float2 mv = *(const float2*)&hg[(size_t)oj*KD + lane*2];  // coalesced 512B row
      a0 += pj*mv.x; a1 += pj*mv.y;
    }
  }
  #pragma unroll
  for (int off = 32; off; off >>= 1) l += __shfl_xor(l, off);
  float inv = 1.f/(l + 1e-16f);
  a0 = elu_(a0*inv); a1 = elu_(a1*inv);
  *(float2*)&out[(size_t)gw*KD + lane*2] = make_float2(a0, a1);
}

// ---------- 1/(||row||+1e-12), one wave per row ----------
__global__ void k_invnorm(const float* __restrict__ x, float* __restrict__ inv, int n) {
  int row = (blockIdx.x*blockDim.x + threadIdx.x) >> 6;
  int lane = threadIdx.x & 63;
  if (row >= n) return;
  float2 v = *(const float2*)&x[(size_t)row*KD + lane*2];
  float s = v.x*v.x + v.y*v.y;
  #pragma unroll
  for (int off = 32; off; off >>= 1) s += __shfl_xor(s, off);
  if (lane == 0) inv[row] = 1.f/(sqrtf(s) + 1e-12f);
}

// ---------- similarity GEMM (both stu/exer pairs via blockIdx.z) ----------
__global__ __launch_bounds__(256)
void k_sim(const float* __restrict__ eoutAll, const float* __restrict__ inv_all,
           float* __restrict__ zbuf, float* __restrict__ dg_all) {
  __shared__ float As[32][68], Bs[32][68];   // [k][row], stride 68 (272B, 16B-aligned)
  __shared__ float red[64][17];
  int z = blockIdx.z;
  const float* A = eoutAll + ((size_t)NNODE   + (size_t)z*NS)*KD;   // v1 part
  const float* B = eoutAll + ((size_t)2*NNODE + (size_t)z*NS)*KD;   // v2 part
  const float* invA = inv_all + z*NS;
  const float* invB = inv_all + NNODE + z*NS;
  float* rowsum = zbuf + z*NS;
  float* colsum = zbuf + 2*NS + z*NS;
  float* diag = dg_all + z*NS;
  int tid = threadIdx.x, tx = tid & 15, ty = tid >> 4;
  int i0 = blockIdx.x*64, j0 = blockIdx.y*64;
  float acc[4][4] = {};
  for (int kc = 0; kc < KD; kc += 32) {
    for (int l = tid; l < 64*32; l += 256) {
      int r = l >> 5, k = l & 31;
      As[k][r] = A[(size_t)(i0 + r)*KD + kc + k];
      Bs[k][r] = B[(size_t)(j0 + r)*KD + kc + k];
    }
    __syncthreads();
    #pragma unroll
    for (int k = 0; k < 32; k++) {
      float4 a4 = *(const float4*)&As[k][ty*4];
      float4 b4 = *(const float4*)&Bs[k][tx*4];
      float a[4] = {a4.x, a4.y, a4.z, a4.w};
      float b[4] = {b4.x, b4.y, b4.z, b4.w};
      #pragma unroll
      for (int u = 0; u < 4; u++)
        #pragma unroll
        for (int v = 0; v < 4; v++) acc[u][v] += a[u]*b[v];
    }
    __syncthreads();
  }
  float ia[4], ib[4], rsum[4] = {0,0,0,0}, csum[4] = {0,0,0,0};
  for (int u = 0; u < 4; u++) ia[u] = invA[i0 + ty*4 + u];
  for (int v = 0; v < 4; v++) ib[v] = invB[j0 + tx*4 + v];
  for (int u = 0; u < 4; u++)
    for (int v = 0; v < 4; v++) {
      float sim2 = acc[u][v]*ia[u]*ib[v]*2.0f;   // sim/tau, tau=0.5
      int gi = i0 + ty*4 + u, gj = j0 + tx*4 + v;
      if (gi == gj) diag[gi] = sim2;
      float e = __expf(sim2);
      rsum[u] += e; csum[v] += e;
    }
  for (int u = 0; u < 4; u++) red[ty*4 + u][tx] = rsum[u];
  __syncthreads();
  if (tid < 64) {
    float s = 0; for (int x = 0; x < 16; x++) s += red[tid][x];
    atomicAdd(&rowsum[i0 + tid], s);
  }
  __syncthreads();
  for (int v = 0; v < 4; v++) red[tx*4 + v][ty] = csum[v];
  __syncthreads();
  if (tid < 64) {
    float s = 0; for (int x = 0; x < 16; x++) s += red[tid][x];
    atomicAdd(&colsum[j0 + tid], s);
  }
}

__global__ void k_loss(const float* __restrict__ zbuf, const float* __restrict__ dg_all,
                       float* __restrict__ loss) {
  __shared__ float red[256];
  int z = blockIdx.y;
  const float* rowsum = zbuf + z*NS;
  const float* colsum = zbuf + 2*NS + z*NS;
  const float* diag = dg_all + z*NS;
  int i = blockIdx.x*256 + threadIdx.x;
  float v = 0.f;
  if (i < NS) v = (logf(rowsum[i]) - diag[i]) + (logf(colsum[i]) - diag[i]);
  red[threadIdx.x] = v; __syncthreads();
  for (int off = 128; off > 0; off >>= 1) {
    if (threadIdx.x < off) red[threadIdx.x] += red[threadIdx.x + off];
    __syncthreads();
  }
  if (threadIdx.x == 0) atomicAdd(loss, 0.1f*red[0]/(float)NS);
}

// X[b][:] = P[si[b]][:] - D[ei[b]][:]
__global__ void k_gatherx(const float* __restrict__ PD, const int* __restrict__ si,
                          const int* __restrict__ ei, float* __restrict__ X) {
  int idx = blockIdx.x*256 + threadIdx.x;
  int b = idx >> 7, cc = idx & 127;
  X[idx] = PD[(size_t)si[b]*KD + cc] - PD[(size_t)(NS + ei[b])*KD + cc];
}

__global__ void k_copy1(const float* __restrict__ src, float* __restrict__ dst) { dst[0] = src[0]; }

extern "C" void kernel_launch(void* const* d_in, const int* in_sizes, int n_in,
                              void* d_out, int out_size, void* d_ws, size_t ws_size,
                              hipStream_t stream) {
  const float* E_stu  = (const float*)d_in[0];
  const float* E_exer = (const float*)d_in[1];
  const float* E_k    = (const float*)d_in[2];
  const float* W1  = (const float*)d_in[3];
  const float* a1s = (const float*)d_in[4];
  const float* a1d = (const float*)d_in[5];
  const float* W2  = (const float*)d_in[6];
  const float* a2s = (const float*)d_in[7];
  const float* a2d = (const float*)d_in[8];
  const float* pW1 = (const float*)d_in[9];
  const float* pW2 = (const float*)d_in[10];
  const float* pW3 = (const float*)d_in[11];
  const float* pb3 = (const float*)d_in[12];
  const float* kn_r = (const float*)d_in[13];
  const int* stu_ids  = (const int*)d_in[14];
  const int* exer_ids = (const int*)d_in[15];
  const int* k_ids    = (const int*)d_in[16];
  EdgePtrs ep;
  for (int g = 0; g < 3; g++) {
    ep.s_src[g] = (const int*)d_in[17 + g*4];
    ep.s_dst[g] = (const int*)d_in[18 + g*4];
    ep.e_src[g] = (const int*)d_in[19 + g*4];
    ep.e_dst[g] = (const int*)d_in[20 + g*4];
  }
  const int* stu_index  = (const int*)d_in[29];
  const int* exer_index = (const int*)d_in[30];
  float* out = (float*)d_out;   // [0..8191] predictions, [8192] closs

  // ---- workspace carve (~43 MB) ----
  char* p = (char*)d_ws;
  auto carve = [&](size_t bytes) -> char* {
    char* r = p; p += (bytes + 255) & ~(size_t)255; return r;
  };
  const size_t NODE_F = (size_t)NNODE*KD;
  // R1: phase A = e0 + h0 + ss0/sd0 ; phase B (after layer-1 agg) = h3 + ss3/sd3
  float* R1 = (float*)carve((3*NODE_F + 6*NNODE)*4);
  float* e0  = R1;
  float* h0  = R1 + NODE_F;
  float* ss0 = R1 + 2*NODE_F;
  float* sd0 = ss0 + NNODE;
  float* h3  = R1;                       // aliases e0/h0 (dead by then)
  float* ss3 = R1 + 3*NODE_F;
  float* sd3 = ss3 + 3*NNODE;
  // C: etmp3 (layer-1 output) ; later PD (4 MB) + X (4 MB), etmp3 dead
  float* Creg = (float*)carve(3*NODE_F*4);
  float* etmp3 = Creg;
  float* PD = Creg;
  float* X  = Creg + NODE_F;
  float* eoutAll = (float*)carve(3*NODE_F*4);
  int* cnt_all = (int*)carve((size_t)3*NNODE*4);
  int* fill    = (int*)carve((size_t)3*NNODE*4);   // contiguous with cnt_all (size %256==0)
  int* rp_all  = (int*)carve((size_t)3*RP*4);
  int* col_all = (int*)carve((size_t)3*NCSR*4);
  float* pWT = (float*)carve((size_t)3*KD*KD*4);
  float* pW1T = pWT, *pW2T = pWT + KD*KD, *pW3T = pWT + 2*KD*KD;
  float* inv_all = (float*)carve((size_t)2*NNODE*4);
  float* zbuf = (float*)carve((4*NS + 64)*4);      // rs[2][NS], cs[2][NS], loss
  float* lossbuf = zbuf + 4*NS;
  float* dg_all = (float*)carve((size_t)2*NS*4);

  // ---- zero init ----
  hipMemsetAsync(cnt_all, 0, (size_t)6*NNODE*4, stream);   // cnt + fill
  hipMemsetAsync(zbuf, 0, (4*NS + 64)*4, stream);

  // ---- gather + CSR build + weight transpose ----
  k_gather<<<NNODE, KD, 0, stream>>>(E_stu, E_exer, E_k, stu_ids, exer_ids, k_ids, e0);
  k_hist<<<dim3(512, 3), 256, 0, stream>>>(ep, cnt_all);
  k_scan<<<3, 1024, 0, stream>>>(cnt_all, rp_all);
  k_scatter<<<dim3(512, 3), 256, 0, stream>>>(ep, rp_all, fill, col_all);
  k_tr<<<dim3(4, 4, 3), dim3(32, 8), 0, stream>>>(pW1, pW2, pW3, pWT);

  // ---- GAT: layer-1 hgemm is graph-independent (computed once) ----
  k_ngemm<0><<<NNODE/32, 256, 0, stream>>>(e0, W1, W1, a1s, a1d, h0, ss0, sd0, NNODE);
  k_agg<<<3*NNODE/4, 256, 0, stream>>>(rp_all, col_all, h0, ss0, sd0, etmp3, 1);
  k_ngemm<0><<<3*NNODE/32, 256, 0, stream>>>(etmp3, W2, W2, a2s, a2d, h3, ss3, sd3, 3*NNODE);
  k_agg<<<3*NNODE/4, 256, 0, stream>>>(rp_all, col_all, h3, ss3, sd3, eoutAll, 0);

  // ---- contrastive loss (v1 = graph1, v2 = graph2) ----
  k_invnorm<<<2*NNODE/4, 256, 0, stream>>>(eoutAll + NODE_F, inv_all, 2*NNODE);
  k_sim<<<dim3(64, 64, 2), 256, 0, stream>>>(eoutAll, inv_all, zbuf, dg_all);
  k_loss<<<dim3(16, 2), 256, 0, stream>>>(zbuf, dg_all, lossbuf);

  // ---- prediction head: per-node P|D, gather-diff, fused final GEMM ----
  k_ngemm<1><<<(2*NS)/32, 256, 0, stream>>>(eoutAll, pW1T, pW2T, pb3, kn_r, PD,
                                            nullptr, nullptr, 2*NS);
  k_gatherx<<<BQ*KD/256, 256, 0, stream>>>(PD, stu_index, exer_index, X);
  k_ngemm<2><<<BQ/32, 256, 0, stream>>>(X, pW3T, pW3T, pb3, kn_r, out,
                                        nullptr, nullptr, BQ);
  k_copy1<<<1, 1, 0, stream>>>(lossbuf, out + BQ);
}

// Round 3
// 563.795 us; speedup vs baseline: 2.5265x; 1.2021x over previous
//
#include <hip/hip_runtime.h>
#include <hip/hip_bf16.h>
#include <math.h>

#define KD 128
#define NS 4096
#define NE 4096
#define NK 128
#define NNODE (NS + NE + NK)      // 8320
#define ESE 131072
#define EEK 16384
#define NCSR (2*ESE + 2*EEK)      // 294912
#define BQ 8192
#define RP (NNODE + 1)

typedef __attribute__((ext_vector_type(8))) short short8;   // 8 bf16 (4 VGPRs)
typedef __attribute__((ext_vector_type(4))) float float4_;  // 4 fp32 acc

__device__ __forceinline__ float lrelu_(float x){ return x >= 0.f ? x : 0.2f*x; }
__device__ __forceinline__ float elu_(float x){ return x > 0.f ? x : __expf(x) - 1.f; }
__device__ __forceinline__ float sigm_(float x){ return 1.f/(1.f + __expf(-x)); }

struct EdgePtrs { const int* s_src[3]; const int* s_dst[3]; const int* e_src[3]; const int* e_dst[3]; };

// ---------- gather initial embeddings into unified node table ----------
__global__ void k_gather(const float* __restrict__ Es, const float* __restrict__ Ee,
                         const float* __restrict__ Ek, const int* __restrict__ sid,
                         const int* __restrict__ eid, const int* __restrict__ kid,
                         float* __restrict__ e0) {
  int i = blockIdx.x, t = threadIdx.x;     // grid NNODE, block KD
  const float* src; int r;
  if (i < NS)            { src = Es; r = sid[i]; }
  else if (i < NS + NE)  { src = Ee; r = eid[i - NS]; }
  else                   { src = Ek; r = kid[i - NS - NE]; }
  e0[(size_t)i*KD + t] = src[(size_t)r*KD + t];
}

// ---------- CSR build (all 3 graphs batched via blockIdx.y) ----------
__global__ void k_hist(EdgePtrs ep, int* __restrict__ cnt_all) {
  int g = blockIdx.y;
  int i = blockIdx.x*256 + threadIdx.x;
  int* cnt = cnt_all + g*NNODE;
  if (i < ESE) {
    atomicAdd(&cnt[ep.s_src[g][i]], 1);
    atomicAdd(&cnt[NS + ep.s_dst[g][i]], 1);
  }
  if (i < EEK) {
    atomicAdd(&cnt[NS + ep.e_src[g][i]], 1);
    atomicAdd(&cnt[NS + NE + ep.e_dst[g][i]], 1);
  }
}

__global__ void k_scan(const int* __restrict__ cnt_all, int* __restrict__ rp_all) {
  __shared__ int sums[1024];
  const int CH = (NNODE + 1023) / 1024;    // 9
  int g = blockIdx.x;
  const int* cnt = cnt_all + g*NNODE;
  int* row_ptr = rp_all + g*RP;
  int t = threadIdx.x;
  int base = t * CH;
  int local[CH];
  int s = 0;
  for (int j = 0; j < CH; j++) {
    int v = (base + j < NNODE) ? cnt[base + j] : 0;
    local[j] = s; s += v;
  }
  sums[t] = s; __syncthreads();
  for (int off = 1; off < 1024; off <<= 1) {
    int v = (t >= off) ? sums[t - off] : 0;
    __syncthreads();
    sums[t] += v;
    __syncthreads();
  }
  int excl = (t == 0) ? 0 : sums[t - 1];
  for (int j = 0; j < CH; j++)
    if (base + j < NNODE) row_ptr[base + j] = excl + local[j];
  if (t == 1023) row_ptr[NNODE] = sums[1023];
}

__global__ void k_scatter(EdgePtrs ep, const int* __restrict__ rp_all,
                          int* __restrict__ fill_all, int* __restrict__ col_all) {
  int g = blockIdx.y;
  int i = blockIdx.x*256 + threadIdx.x;
  const int* row_ptr = rp_all + g*RP;
  int* fill = fill_all + g*NNODE;
  int* col = col_all + (size_t)g*NCSR;
  if (i < ESE) {
    int s = ep.s_src[g][i], d = NS + ep.s_dst[g][i];
    col[row_ptr[s] + atomicAdd(&fill[s], 1)] = d;
    col[row_ptr[d] + atomicAdd(&fill[d], 1)] = s;
  }
  if (i < EEK) {
    int s = NS + ep.e_src[g][i], d = NS + NE + ep.e_dst[g][i];
    col[row_ptr[s] + atomicAdd(&fill[s], 1)] = d;
    col[row_ptr[d] + atomicAdd(&fill[d], 1)] = s;
  }
}

// ---------- transpose the 3 head weight matrices ----------
__global__ void k_tr(const float* __restrict__ pW1, const float* __restrict__ pW2,
                     const float* __restrict__ pW3, float* __restrict__ T) {
  __shared__ float tile[32][33];
  int m = blockIdx.z;
  const float* src = m == 0 ? pW1 : (m == 1 ? pW2 : pW3);
  float* dst = T + m*KD*KD;
  int bx = blockIdx.x*32, by = blockIdx.y*32;
  int tx = threadIdx.x, ty = threadIdx.y;   // block (32,8)
  for (int j = 0; j < 32; j += 8)
    tile[ty + j][tx] = src[(by + ty + j)*KD + bx + tx];
  __syncthreads();
  for (int j = 0; j < 32; j += 8)
    dst[(bx + ty + j)*KD + by + tx] = tile[tx][ty + j];
}

// ---------- register-blocked node GEMM ----------
// MODE 0: out = in@Wa (no act) + fused ss/sd (v1=a_s, v2=a_d)
// MODE 1: out = sigm(in@W), W = (blockIdx < grid/2 ? Wa : Wb)   (P|D batched)
// MODE 2: head: o = sigm(in@Wa + v1[bias]); out[row] = sum(o*v2[row,:])/sum(v2[row,:])
template<int MODE>
__global__ __launch_bounds__(256)
void k_ngemm(const float* __restrict__ in, const float* __restrict__ Wa,
             const float* __restrict__ Wb,
             const float* __restrict__ v1, const float* __restrict__ v2,
             float* __restrict__ out, float* __restrict__ ss, float* __restrict__ sd,
             int nrows) {
  __shared__ float ers[32][KD];
  int t = threadIdx.x;
  int row0 = blockIdx.x * 32;
  const float* Wm = (MODE == 1 && blockIdx.x >= (gridDim.x >> 1)) ? Wb : Wa;
  for (int i = t; i < 32*KD; i += 256) {
    int r = i >> 7, k = i & 127;
    int gr = row0 + r;
    ers[r][k] = (gr < nrows) ? in[(size_t)gr*KD + k] : 0.f;
  }
  __syncthreads();
  int w = t >> 6, c = t & 63;
  float acc0[8] = {0,0,0,0,0,0,0,0}, acc1[8] = {0,0,0,0,0,0,0,0};
  #pragma unroll 2
  for (int kc = 0; kc < KD; kc += 4) {
    float wa[4], wb[4];
    #pragma unroll
    for (int j = 0; j < 4; j++) {
      wa[j] = Wm[(kc + j)*KD + c];
      wb[j] = Wm[(kc + j)*KD + c + 64];
    }
    #pragma unroll
    for (int r = 0; r < 8; r++) {
      float4 e = *(const float4*)&ers[w*8 + r][kc];   // wave-uniform broadcast read
      acc0[r] += e.x*wa[0] + e.y*wa[1] + e.z*wa[2] + e.w*wa[3];
      acc1[r] += e.x*wb[0] + e.y*wb[1] + e.z*wb[2] + e.w*wb[3];
    }
  }
  if (MODE == 0) {
    float as1 = v1[c], as2 = v1[c + 64], ad1 = v2[c], ad2 = v2[c + 64];
    #pragma unroll
    for (int r = 0; r < 8; r++) {
      int gr = row0 + w*8 + r;
      if (gr < nrows) {
        out[(size_t)gr*KD + c] = acc0[r];
        out[(size_t)gr*KD + c + 64] = acc1[r];
      }
      float s = acc0[r]*as1 + acc1[r]*as2;
      float d = acc0[r]*ad1 + acc1[r]*ad2;
      #pragma unroll
      for (int off = 32; off; off >>= 1) { s += __shfl_xor(s, off); d += __shfl_xor(d, off); }
      if (c == 0 && gr < nrows) { ss[gr] = s; sd[gr] = d; }
    }
  } else if (MODE == 1) {
    #pragma unroll
    for (int r = 0; r < 8; r++) {
      int gr = row0 + w*8 + r;
      if (gr < nrows) {
        out[(size_t)gr*KD + c] = sigm_(acc0[r]);
        out[(size_t)gr*KD + c + 64] = sigm_(acc1[r]);
      }
    }
  } else {
    float b1 = v1[c], b2 = v1[c + 64];
    #pragma unroll
    for (int r = 0; r < 8; r++) {
      int gr = row0 + w*8 + r;
      if (gr < nrows) {
        float kr1 = v2[(size_t)gr*KD + c], kr2 = v2[(size_t)gr*KD + c + 64];
        float o1 = sigm_(acc0[r] + b1), o2 = sigm_(acc1[r] + b2);
        float num = o1*kr1 + o2*kr2, den = kr1 + kr2;
        #pragma unroll
        for (int off = 32; off; off >>= 1) { num += __shfl_xor(num, off); den += __shfl_xor(den, off); }
        if (c == 0) out[gr] = num/den;
      }
    }
  }
}

// ---------- segment-softmax aggregation, 3 graphs batched; one wave/node ----------
__global__ void k_agg(const int* __restrict__ rp_all, const int* __restrict__ col_all,
                      const float* __restrict__ h, const float* __restrict__ ss,
                      const float* __restrict__ sd, float* __restrict__ out,
                      int shared_h) {
  int gw = blockIdx.x*4 + (threadIdx.x >> 6);
  int lane = threadIdx.x & 63;
  if (gw >= 3*NNODE) return;
  int g = gw / NNODE;
  int node = gw - g*NNODE;
  const int* rp = rp_all + g*RP;
  const int* cl = col_all + (size_t)g*NCSR;
  const float* hg  = shared_h ? h  : h  + (size_t)g*NNODE*KD;
  const float* ssg = shared_h ? ss : ss + g*NNODE;
  const float* sdg = shared_h ? sd : sd + g*NNODE;
  int e0 = rp[node], e1 = rp[node + 1];
  float sdv = sdg[node];
  // lane-parallel max
  float m = -INFINITY;
  for (int e = e0 + lane; e < e1; e += 64)
    m = fmaxf(m, lrelu_(ssg[cl[e]] + sdv));
  #pragma unroll
  for (int off = 32; off; off >>= 1) m = fmaxf(m, __shfl_xor(m, off));
  // lane-parallel exp + shuffle-broadcast row accumulation
  float l = 0.f, a0 = 0.f, a1 = 0.f;
  for (int base = e0; base < e1; base += 64) {
    int e = base + lane;
    float p = 0.f; int o = 0;
    if (e < e1) { o = cl[e]; p = __expf(lrelu_(ssg[o] + sdv) - m); }
    l += p;
    int cnt = min(64, e1 - base);
    for (int j = 0; j < cnt; j++) {
      float pj = __shfl(p, j);
      int oj = __shfl(o, j);
      float2 mv = *(const float2*)&hg[(size_t)oj*KD + lane*2];  // coalesced 512B row
      a0 += pj*mv.x; a1 += pj*mv.y;
    }
  }
  #pragma unroll
  for (int off = 32; off; off >>= 1) l += __shfl_xor(l, off);
  float inv = 1.f/(l + 1e-16f);
  a0 = elu_(a0*inv); a1 = elu_(a1*inv);
  *(float2*)&out[(size_t)gw*KD + lane*2] = make_float2(a0, a1);
}

// ---------- fused normalize + bf16 cast: Z[view][row][:] = h_row/||h_row|| ----------
__global__ void k_znorm(const float* __restrict__ eoutAll, unsigned short* __restrict__ Z) {
  int gw = blockIdx.x*4 + (threadIdx.x >> 6);   // 2*8192 waves
  int lane = threadIdx.x & 63;
  if (gw >= 2*(NS + NE)) return;
  int view = gw >> 13;          // 0 = v1(g1), 1 = v2(g2)
  int row = gw & 8191;          // node index (stu 0..4095 | exer 4096..8191)
  const float* src = eoutAll + (size_t)(1 + view)*NNODE*KD + (size_t)row*KD;
  float2 v = *(const float2*)&src[lane*2];
  float s = v.x*v.x + v.y*v.y;
  #pragma unroll
  for (int off = 32; off; off >>= 1) s += __shfl_xor(s, off);
  float inv = 1.f/(sqrtf(s) + 1e-12f);
  __hip_bfloat16 b0 = __float2bfloat16(v.x*inv);
  __hip_bfloat16 b1 = __float2bfloat16(v.y*inv);
  ushort2 pk; pk.x = *(unsigned short*)&b0; pk.y = *(unsigned short*)&b1;
  *(ushort2*)&Z[((size_t)view*8192 + row)*KD + lane*2] = pk;
}

// ---------- bf16 MFMA similarity GEMM with fused exp/rowsum/colsum/diag ----------
// grid (32,32,2), block 256. 128x128 tile, K=128 (no K loop), XOR-swizzled LDS.
__global__ __launch_bounds__(256)
void k_sim(const unsigned short* __restrict__ Z, float* __restrict__ zbuf,
           float* __restrict__ dg_all) {
  __shared__ unsigned short As[128*KD];   // 32 KB, row r: 16 groups of 8, group g at (g ^ (r&15))
  __shared__ unsigned short Bs[128*KD];   // 32 KB
  int z = blockIdx.z;
  int t = threadIdx.x;
  const unsigned short* Arow = Z + ((size_t)z*NS + (size_t)blockIdx.x*128)*KD;
  const unsigned short* Brow = Z + ((size_t)8192 + (size_t)z*NS + (size_t)blockIdx.y*128)*KD;
  #pragma unroll
  for (int j = 0; j < 8; j++) {
    int G = t + j*256;                     // linear 16B-group id, 0..2047
    int r = G >> 4, g = G & 15;
    int sw = g ^ (r & 15);
    *(float4*)&As[(r*16 + sw)*8] = *(const float4*)&Arow[(size_t)G*8];
    *(float4*)&Bs[(r*16 + sw)*8] = *(const float4*)&Brow[(size_t)G*8];
  }
  __syncthreads();
  int w = t >> 6, lane = t & 63;
  int rw = (w >> 1)*64, cw = (w & 1)*64;
  int m15 = lane & 15, quad = lane >> 4;
  float4_ acc[4][4] = {};
  #pragma unroll
  for (int kq = 0; kq < 4; kq++) {
    short8 a[4], b[4];
    int g = kq*4 + quad;
    #pragma unroll
    for (int mi = 0; mi < 4; mi++) {
      int r = rw + mi*16 + m15;
      a[mi] = *(const short8*)&As[(r*16 + (g ^ (r & 15)))*8];
    }
    #pragma unroll
    for (int ni = 0; ni < 4; ni++) {
      int r = cw + ni*16 + m15;
      b[ni] = *(const short8*)&Bs[(r*16 + (g ^ (r & 15)))*8];
    }
    #pragma unroll
    for (int mi = 0; mi < 4; mi++)
      #pragma unroll
      for (int ni = 0; ni < 4; ni++)
        acc[mi][ni] = __builtin_amdgcn_mfma_f32_16x16x32_bf16(a[mi], b[ni], acc[mi][ni], 0, 0, 0);
  }
  // epilogue: sim2 = 2*dot (tau=0.5, inputs pre-normalized)
  int i0 = blockIdx.x*128, j0 = blockIdx.y*128;
  float* rowsum = zbuf + z*NS;
  float* colsum = zbuf + 2*NS + z*NS;
  float* diag = dg_all + z*NS;
  float cs[4] = {0,0,0,0};
  #pragma unroll
  for (int mi = 0; mi < 4; mi++) {
    float rs[4] = {0,0,0,0};
    #pragma unroll
    for (int ni = 0; ni < 4; ni++) {
      #pragma unroll
      for (int reg = 0; reg < 4; reg++) {
        float sim2 = acc[mi][ni][reg]*2.0f;
        int gi = i0 + rw + mi*16 + quad*4 + reg;     // C/D: row=(lane>>4)*4+reg
        int gj = j0 + cw + ni*16 + m15;              //      col=lane&15
        if (gi == gj) diag[gi] = sim2;
        float e = __expf(sim2);
        rs[reg] += e; cs[ni] += e;
      }
    }
    #pragma unroll
    for (int reg = 0; reg < 4; reg++) {
      float v = rs[reg];
      v += __shfl_xor(v, 1); v += __shfl_xor(v, 2);
      v += __shfl_xor(v, 4); v += __shfl_xor(v, 8);
      if (m15 == 0) atomicAdd(&rowsum[i0 + rw + mi*16 + quad*4 + reg], v);
    }
  }
  #pragma unroll
  for (int ni = 0; ni < 4; ni++) {
    float v = cs[ni];
    v += __shfl_xor(v, 16); v += __shfl_xor(v, 32);
    if (quad == 0) atomicAdd(&colsum[j0 + cw + ni*16 + m15], v);
  }
}

__global__ void k_loss(const float* __restrict__ zbuf, const float* __restrict__ dg_all,
                       float* __restrict__ loss) {
  __shared__ float red[256];
  int z = blockIdx.y;
  const float* rowsum = zbuf + z*NS;
  const float* colsum = zbuf + 2*NS + z*NS;
  const float* diag = dg_all + z*NS;
  int i = blockIdx.x*256 + threadIdx.x;
  float v = 0.f;
  if (i < NS) v = (logf(rowsum[i]) - diag[i]) + (logf(colsum[i]) - diag[i]);
  red[threadIdx.x] = v; __syncthreads();
  for (int off = 128; off > 0; off >>= 1) {
    if (threadIdx.x < off) red[threadIdx.x] += red[threadIdx.x + off];
    __syncthreads();
  }
  if (threadIdx.x == 0) atomicAdd(loss, 0.1f*red[0]/(float)NS);
}

// X[b][:] = P[si[b]][:] - D[ei[b]][:]
__global__ void k_gatherx(const float* __restrict__ PD, const int* __restrict__ si,
                          const int* __restrict__ ei, float* __restrict__ X) {
  int idx = blockIdx.x*256 + threadIdx.x;
  int b = idx >> 7, cc = idx & 127;
  X[idx] = PD[(size_t)si[b]*KD + cc] - PD[(size_t)(NS + ei[b])*KD + cc];
}

__global__ void k_copy1(const float* __restrict__ src, float* __restrict__ dst) { dst[0] = src[0]; }

extern "C" void kernel_launch(void* const* d_in, const int* in_sizes, int n_in,
                              void* d_out, int out_size, void* d_ws, size_t ws_size,
                              hipStream_t stream) {
  const float* E_stu  = (const float*)d_in[0];
  const float* E_exer = (const float*)d_in[1];
  const float* E_k    = (const float*)d_in[2];
  const float* W1  = (const float*)d_in[3];
  const float* a1s = (const float*)d_in[4];
  const float* a1d = (const float*)d_in[5];
  const float* W2  = (const float*)d_in[6];
  const float* a2s = (const float*)d_in[7];
  const float* a2d = (const float*)d_in[8];
  const float* pW1 = (const float*)d_in[9];
  const float* pW2 = (const float*)d_in[10];
  const float* pW3 = (const float*)d_in[11];
  const float* pb3 = (const float*)d_in[12];
  const float* kn_r = (const float*)d_in[13];
  const int* stu_ids  = (const int*)d_in[14];
  const int* exer_ids = (const int*)d_in[15];
  const int* k_ids    = (const int*)d_in[16];
  EdgePtrs ep;
  for (int g = 0; g < 3; g++) {
    ep.s_src[g] = (const int*)d_in[17 + g*4];
    ep.s_dst[g] = (const int*)d_in[18 + g*4];
    ep.e_src[g] = (const int*)d_in[19 + g*4];
    ep.e_dst[g] = (const int*)d_in[20 + g*4];
  }
  const int* stu_index  = (const int*)d_in[29];
  const int* exer_index = (const int*)d_in[30];
  float* out = (float*)d_out;   // [0..8191] predictions, [8192] closs

  // ---- workspace carve (~47 MB) ----
  char* p = (char*)d_ws;
  auto carve = [&](size_t bytes) -> char* {
    char* r = p; p += (bytes + 255) & ~(size_t)255; return r;
  };
  const size_t NODE_F = (size_t)NNODE*KD;
  float* R1 = (float*)carve((3*NODE_F + 6*NNODE)*4);
  float* e0  = R1;
  float* h0  = R1 + NODE_F;
  float* ss0 = R1 + 2*NODE_F;
  float* sd0 = ss0 + NNODE;
  float* h3  = R1;                       // aliases e0/h0 (dead by then)
  float* ss3 = R1 + 3*NODE_F;
  float* sd3 = ss3 + 3*NNODE;
  float* Creg = (float*)carve(3*NODE_F*4);
  float* etmp3 = Creg;
  float* PD = Creg;
  float* X  = Creg + NODE_F;
  float* eoutAll = (float*)carve(3*NODE_F*4);
  int* cnt_all = (int*)carve((size_t)3*NNODE*4);
  int* fill    = (int*)carve((size_t)3*NNODE*4);
  int* rp_all  = (int*)carve((size_t)3*RP*4);
  int* col_all = (int*)carve((size_t)3*NCSR*4);
  float* pWT = (float*)carve((size_t)3*KD*KD*4);
  float* pW1T = pWT, *pW2T = pWT + KD*KD, *pW3T = pWT + 2*KD*KD;
  float* zbuf = (float*)carve((4*NS + 64)*4);      // rs[2][NS], cs[2][NS], loss
  float* lossbuf = zbuf + 4*NS;
  float* dg_all = (float*)carve((size_t)2*NS*4);
  unsigned short* Z = (unsigned short*)carve((size_t)2*8192*KD*2);  // bf16 Z1|Z2

  // ---- zero init ----
  hipMemsetAsync(cnt_all, 0, (size_t)6*NNODE*4, stream);   // cnt + fill
  hipMemsetAsync(zbuf, 0, (4*NS + 64)*4, stream);

  // ---- gather + CSR build + weight transpose ----
  k_gather<<<NNODE, KD, 0, stream>>>(E_stu, E_exer, E_k, stu_ids, exer_ids, k_ids, e0);
  k_hist<<<dim3(512, 3), 256, 0, stream>>>(ep, cnt_all);
  k_scan<<<3, 1024, 0, stream>>>(cnt_all, rp_all);
  k_scatter<<<dim3(512, 3), 256, 0, stream>>>(ep, rp_all, fill, col_all);
  k_tr<<<dim3(4, 4, 3), dim3(32, 8), 0, stream>>>(pW1, pW2, pW3, pWT);

  // ---- GAT: layer-1 hgemm is graph-independent (computed once) ----
  k_ngemm<0><<<NNODE/32, 256, 0, stream>>>(e0, W1, W1, a1s, a1d, h0, ss0, sd0, NNODE);
  k_agg<<<3*NNODE/4, 256, 0, stream>>>(rp_all, col_all, h0, ss0, sd0, etmp3, 1);
  k_ngemm<0><<<3*NNODE/32, 256, 0, stream>>>(etmp3, W2, W2, a2s, a2d, h3, ss3, sd3, 3*NNODE);
  k_agg<<<3*NNODE/4, 256, 0, stream>>>(rp_all, col_all, h3, ss3, sd3, eoutAll, 0);

  // ---- contrastive loss (v1 = graph1, v2 = graph2), bf16 MFMA path ----
  k_znorm<<<2*8192/4, 256, 0, stream>>>(eoutAll, Z);
  k_sim<<<dim3(32, 32, 2), 256, 0, stream>>>(Z, zbuf, dg_all);
  k_loss<<<dim3(16, 2), 256, 0, stream>>>(zbuf, dg_all, lossbuf);

  // ---- prediction head: per-node P|D, gather-diff, fused final GEMM ----
  k_ngemm<1><<<(2*NS)/32, 256, 0, stream>>>(eoutAll, pW1T, pW2T, pb3, kn_r, PD,
                                            nullptr, nullptr, 2*NS);
  k_gatherx<<<BQ*KD/256, 256, 0, stream>>>(PD, stu_index, exer_index, X);
  k_ngemm<2><<<BQ/32, 256, 0, stream>>>(X, pW3T, pW3T, pb3, kn_r, out,
                                        nullptr, nullptr, BQ);
  k_copy1<<<1, 1, 0, stream>>>(lossbuf, out + BQ);
}

// Round 4
// 474.110 us; speedup vs baseline: 3.0045x; 1.1892x over previous
//
#include <hip/hip_runtime.h>
#include <hip/hip_bf16.h>
#include <math.h>

#define KD 128
#define NS 4096
#define NE 4096
#define NK 128
#define NNODE (NS + NE + NK)      // 8320
#define ESE 131072
#define EEK 16384
#define NCSR (2*ESE + 2*EEK)      // 294912
#define BQ 8192
#define RP (NNODE + 1)

typedef __attribute__((ext_vector_type(8))) short short8;   // 8 bf16 (4 VGPRs)
typedef __attribute__((ext_vector_type(4))) float float4_;  // 4 fp32 acc

__device__ __forceinline__ float lrelu_(float x){ return x >= 0.f ? x : 0.2f*x; }
__device__ __forceinline__ float elu_(float x){ return x > 0.f ? x : __expf(x) - 1.f; }
__device__ __forceinline__ float sigm_(float x){ return 1.f/(1.f + __expf(-x)); }

struct EdgePtrs { const int* s_src[3]; const int* s_dst[3]; const int* e_src[3]; const int* e_dst[3]; };

// ---------- CSR build (all 3 graphs batched via blockIdx.y) ----------
__global__ void k_hist(EdgePtrs ep, int* __restrict__ cnt_all) {
  int g = blockIdx.y;
  int i = blockIdx.x*256 + threadIdx.x;
  int* cnt = cnt_all + g*NNODE;
  if (i < ESE) {
    atomicAdd(&cnt[ep.s_src[g][i]], 1);
    atomicAdd(&cnt[NS + ep.s_dst[g][i]], 1);
  }
  if (i < EEK) {
    atomicAdd(&cnt[NS + ep.e_src[g][i]], 1);
    atomicAdd(&cnt[NS + NE + ep.e_dst[g][i]], 1);
  }
}

__global__ void k_scan(const int* __restrict__ cnt_all, int* __restrict__ rp_all) {
  __shared__ int sums[1024];
  const int CH = (NNODE + 1023) / 1024;    // 9
  int g = blockIdx.x;
  const int* cnt = cnt_all + g*NNODE;
  int* row_ptr = rp_all + g*RP;
  int t = threadIdx.x;
  int base = t * CH;
  int local[CH];
  int s = 0;
  for (int j = 0; j < CH; j++) {
    int v = (base + j < NNODE) ? cnt[base + j] : 0;
    local[j] = s; s += v;
  }
  sums[t] = s; __syncthreads();
  for (int off = 1; off < 1024; off <<= 1) {
    int v = (t >= off) ? sums[t - off] : 0;
    __syncthreads();
    sums[t] += v;
    __syncthreads();
  }
  int excl = (t == 0) ? 0 : sums[t - 1];
  for (int j = 0; j < CH; j++)
    if (base + j < NNODE) row_ptr[base + j] = excl + local[j];
  if (t == 1023) row_ptr[NNODE] = sums[1023];
}

__global__ void k_scatter(EdgePtrs ep, const int* __restrict__ rp_all,
                          int* __restrict__ fill_all, int* __restrict__ col_all) {
  int g = blockIdx.y;
  int i = blockIdx.x*256 + threadIdx.x;
  const int* row_ptr = rp_all + g*RP;
  int* fill = fill_all + g*NNODE;
  int* col = col_all + (size_t)g*NCSR;
  if (i < ESE) {
    int s = ep.s_src[g][i], d = NS + ep.s_dst[g][i];
    col[row_ptr[s] + atomicAdd(&fill[s], 1)] = d;
    col[row_ptr[d] + atomicAdd(&fill[d], 1)] = s;
  }
  if (i < EEK) {
    int s = NS + ep.e_src[g][i], d = NS + NE + ep.e_dst[g][i];
    col[row_ptr[s] + atomicAdd(&fill[s], 1)] = d;
    col[row_ptr[d] + atomicAdd(&fill[d], 1)] = s;
  }
}

// ---------- transpose the 3 head weight matrices ----------
__global__ void k_tr(const float* __restrict__ pW1, const float* __restrict__ pW2,
                     const float* __restrict__ pW3, float* __restrict__ T) {
  __shared__ float tile[32][33];
  int m = blockIdx.z;
  const float* src = m == 0 ? pW1 : (m == 1 ? pW2 : pW3);
  float* dst = T + m*KD*KD;
  int bx = blockIdx.x*32, by = blockIdx.y*32;
  int tx = threadIdx.x, ty = threadIdx.y;   // block (32,8)
  for (int j = 0; j < 32; j += 8)
    tile[ty + j][tx] = src[(by + ty + j)*KD + bx + tx];
  __syncthreads();
  for (int j = 0; j < 32; j += 8)
    dst[(bx + ty + j)*KD + by + tx] = tile[tx][ty + j];
}

// ---------- register-blocked node GEMM ----------
// MODE 0: out = in@Wa (no act) + fused ss/sd (v1=a_s, v2=a_d)
// MODE 3: like MODE 0 but stages rows gathered from embedding tables (g1..g3 = E tables, i1..i3 = ids)
// MODE 1: out = sigm(in@W), W = (blockIdx < grid/2 ? Wa : Wb)   (P|D batched)
// MODE 2: head: stages X = PD[si]-PD[NS+ei] (g1=PD, i1=si, i2=ei);
//         o = sigm(X@Wa + v1[bias]); out[row] = sum(o*v2[row,:])/sum(v2[row,:])
template<int MODE>
__global__ __launch_bounds__(256)
void k_ngemm(const float* __restrict__ in, const float* __restrict__ Wa,
             const float* __restrict__ Wb,
             const float* __restrict__ v1, const float* __restrict__ v2,
             float* __restrict__ out, float* __restrict__ ss, float* __restrict__ sd,
             int nrows,
             const float* __restrict__ g1, const float* __restrict__ g2,
             const float* __restrict__ g3,
             const int* __restrict__ i1, const int* __restrict__ i2,
             const int* __restrict__ i3) {
  __shared__ float ers[32][KD];
  int t = threadIdx.x;
  int row0 = blockIdx.x * 32;
  const float* Wm = (MODE == 1 && blockIdx.x >= (gridDim.x >> 1)) ? Wb : Wa;
  for (int i = t; i < 32*KD; i += 256) {
    int r = i >> 7, k = i & 127;
    int gr = row0 + r;
    float val;
    if (MODE == 3) {
      const float* srow;
      if (gr < NS)           srow = g1 + (size_t)i1[gr]*KD;
      else if (gr < NS + NE) srow = g2 + (size_t)i2[gr - NS]*KD;
      else                   srow = g3 + (size_t)i3[gr - NS - NE]*KD;
      val = srow[k];
    } else if (MODE == 2) {
      val = g1[(size_t)i1[gr]*KD + k] - g1[(size_t)(NS + i2[gr])*KD + k];
    } else {
      val = (gr < nrows) ? in[(size_t)gr*KD + k] : 0.f;
    }
    ers[r][k] = val;
  }
  __syncthreads();
  int w = t >> 6, c = t & 63;
  float acc0[8] = {0,0,0,0,0,0,0,0}, acc1[8] = {0,0,0,0,0,0,0,0};
  #pragma unroll 2
  for (int kc = 0; kc < KD; kc += 4) {
    float wa[4], wb[4];
    #pragma unroll
    for (int j = 0; j < 4; j++) {
      wa[j] = Wm[(kc + j)*KD + c];
      wb[j] = Wm[(kc + j)*KD + c + 64];
    }
    #pragma unroll
    for (int r = 0; r < 8; r++) {
      float4 e = *(const float4*)&ers[w*8 + r][kc];   // wave-uniform broadcast read
      acc0[r] += e.x*wa[0] + e.y*wa[1] + e.z*wa[2] + e.w*wa[3];
      acc1[r] += e.x*wb[0] + e.y*wb[1] + e.z*wb[2] + e.w*wb[3];
    }
  }
  if (MODE == 0 || MODE == 3) {
    float as1 = v1[c], as2 = v1[c + 64], ad1 = v2[c], ad2 = v2[c + 64];
    #pragma unroll
    for (int r = 0; r < 8; r++) {
      int gr = row0 + w*8 + r;
      if (gr < nrows) {
        out[(size_t)gr*KD + c] = acc0[r];
        out[(size_t)gr*KD + c + 64] = acc1[r];
      }
      float s = acc0[r]*as1 + acc1[r]*as2;
      float d = acc0[r]*ad1 + acc1[r]*ad2;
      #pragma unroll
      for (int off = 32; off; off >>= 1) { s += __shfl_xor(s, off); d += __shfl_xor(d, off); }
      if (c == 0 && gr < nrows) { ss[gr] = s; sd[gr] = d; }
    }
  } else if (MODE == 1) {
    #pragma unroll
    for (int r = 0; r < 8; r++) {
      int gr = row0 + w*8 + r;
      if (gr < nrows) {
        out[(size_t)gr*KD + c] = sigm_(acc0[r]);
        out[(size_t)gr*KD + c + 64] = sigm_(acc1[r]);
      }
    }
  } else {
    float b1 = v1[c], b2 = v1[c + 64];
    #pragma unroll
    for (int r = 0; r < 8; r++) {
      int gr = row0 + w*8 + r;
      float kr1 = v2[(size_t)gr*KD + c], kr2 = v2[(size_t)gr*KD + c + 64];
      float o1 = sigm_(acc0[r] + b1), o2 = sigm_(acc1[r] + b2);
      float num = o1*kr1 + o2*kr2, den = kr1 + kr2;
      #pragma unroll
      for (int off = 32; off; off >>= 1) { num += __shfl_xor(num, off); den += __shfl_xor(den, off); }
      if (c == 0) out[gr] = num/den;
    }
  }
}

// ---------- segment-softmax aggregation, 3 graphs batched ----------
// One wave per (graph,node). 4 edge-subgroups x 16 feature-lanes: 8 independent
// 16B loads in flight per iteration (vs 1 rolled load before) -> hides L2 latency.
// Zo == nullptr  => layer 1 (shared h across graphs, write all fp32 rows)
// Zo != nullptr  => layer 2 (per-graph h; skip k rows; g0 -> fp32 out only,
//                  g1/g2 -> fused normalize+bf16 Z only)
__global__ void k_agg(const int* __restrict__ rp_all, const int* __restrict__ col_all,
                      const float* __restrict__ h, const float* __restrict__ ss,
                      const float* __restrict__ sd, float* __restrict__ out,
                      unsigned short* __restrict__ Zo) {
  int gw = blockIdx.x*4 + (threadIdx.x >> 6);
  int lane = threadIdx.x & 63;
  if (gw >= 3*NNODE) return;
  int g = gw / NNODE;
  int node = gw - g*NNODE;
  bool layer2 = (Zo != nullptr);
  if (layer2 && node >= NS + NE) return;        // k rows unused after layer 2
  const int* rp = rp_all + g*RP;
  const int* cl = col_all + (size_t)g*NCSR;
  const float* hg  = layer2 ? h  + (size_t)g*NNODE*KD : h;
  const float* ssg = layer2 ? ss + g*NNODE : ss;
  const float* sdg = layer2 ? sd + g*NNODE : sd;
  int e0 = rp[node], e1 = rp[node + 1];
  float sdv = sdg[node];
  int sub = lane >> 4;       // edge subgroup 0..3
  int fl  = lane & 15;       // feature lane: features fl*8 .. fl*8+7
  // pass 1: lane-parallel max
  float m = -INFINITY;
  for (int e = e0 + lane; e < e1; e += 64)
    m = fmaxf(m, lrelu_(ssg[cl[e]] + sdv));
  #pragma unroll
  for (int off = 32; off; off >>= 1) m = fmaxf(m, __shfl_xor(m, off));
  // pass 2: lane-parallel exp; 4-edge-parallel gather/accumulate
  float l = 0.f;
  float4 A0 = {0,0,0,0}, A1 = {0,0,0,0};
  for (int base = e0; base < e1; base += 64) {
    int e = base + lane;
    float p = 0.f; int o = 0;
    if (e < e1) { o = cl[e]; p = __expf(lrelu_(ssg[o] + sdv) - m); }
    l += p;
    int cnt = min(64, e1 - base);
    for (int j = 0; j*4 < cnt; j++) {
      int idx = j*4 + sub;
      float pj = __shfl(p, idx);
      int oj = __shfl(o, idx);
      if (idx < cnt) {
        const float* row = &hg[(size_t)oj*KD + fl*8];
        float4 v0 = *(const float4*)row;
        float4 v1 = *(const float4*)(row + 4);
        A0.x += pj*v0.x; A0.y += pj*v0.y; A0.z += pj*v0.z; A0.w += pj*v0.w;
        A1.x += pj*v1.x; A1.y += pj*v1.y; A1.z += pj*v1.z; A1.w += pj*v1.w;
      }
    }
  }
  #pragma unroll
  for (int off = 32; off; off >>= 1) l += __shfl_xor(l, off);
  // reduce across the 4 edge-subgroups (lanes differing in bits 4,5)
  #pragma unroll
  for (int off = 16; off <= 32; off <<= 1) {
    A0.x += __shfl_xor(A0.x, off); A0.y += __shfl_xor(A0.y, off);
    A0.z += __shfl_xor(A0.z, off); A0.w += __shfl_xor(A0.w, off);
    A1.x += __shfl_xor(A1.x, off); A1.y += __shfl_xor(A1.y, off);
    A1.z += __shfl_xor(A1.z, off); A1.w += __shfl_xor(A1.w, off);
  }
  float inv = 1.f/(l + 1e-16f);
  float av[8];
  av[0] = elu_(A0.x*inv); av[1] = elu_(A0.y*inv); av[2] = elu_(A0.z*inv); av[3] = elu_(A0.w*inv);
  av[4] = elu_(A1.x*inv); av[5] = elu_(A1.y*inv); av[6] = elu_(A1.z*inv); av[7] = elu_(A1.w*inv);
  if (!layer2 || g == 0) {
    float* orow = &out[(size_t)gw*KD];
    if (sub == 0) *(float4*)&orow[fl*8]     = make_float4(av[0], av[1], av[2], av[3]);
    else if (sub == 1) *(float4*)&orow[fl*8 + 4] = make_float4(av[4], av[5], av[6], av[7]);
  }
  if (layer2 && g >= 1) {
    // fused normalize + bf16 cast (replaces k_znorm)
    float nrm = av[0]*av[0] + av[1]*av[1] + av[2]*av[2] + av[3]*av[3]
              + av[4]*av[4] + av[5]*av[5] + av[6]*av[6] + av[7]*av[7];
    #pragma unroll
    for (int off = 1; off <= 8; off <<= 1) nrm += __shfl_xor(nrm, off);
    float invn = 1.f/(sqrtf(nrm) + 1e-12f);
    unsigned short us[8];
    #pragma unroll
    for (int i = 0; i < 8; i++) {
      __hip_bfloat16 b = __float2bfloat16(av[i]*invn);
      us[i] = *(unsigned short*)&b;
    }
    if (sub == 0) {
      unsigned short* zr = Zo + ((size_t)(g - 1)*8192 + node)*KD + fl*8;
      ushort4 u0; u0.x = us[0]; u0.y = us[1]; u0.z = us[2]; u0.w = us[3];
      ushort4 u1; u1.x = us[4]; u1.y = us[5]; u1.z = us[6]; u1.w = us[7];
      *(ushort4*)zr = u0;
      *(ushort4*)(zr + 4) = u1;
    }
  }
}

// ---------- bf16 MFMA similarity GEMM with fused exp/rowsum/colsum/diag ----------
// grid (32,32,2), block 256. 128x128 tile, K=128 (no K loop), XOR-swizzled LDS.
__global__ __launch_bounds__(256)
void k_sim(const unsigned short* __restrict__ Z, float* __restrict__ zbuf,
           float* __restrict__ dg_all) {
  __shared__ unsigned short As[128*KD];   // 32 KB, row r: 16 groups of 8, group g at (g ^ (r&15))
  __shared__ unsigned short Bs[128*KD];   // 32 KB
  int z = blockIdx.z;
  int t = threadIdx.x;
  const unsigned short* Arow = Z + ((size_t)z*NS + (size_t)blockIdx.x*128)*KD;
  const unsigned short* Brow = Z + ((size_t)8192 + (size_t)z*NS + (size_t)blockIdx.y*128)*KD;
  #pragma unroll
  for (int j = 0; j < 8; j++) {
    int G = t + j*256;                     // linear 16B-group id, 0..2047
    int r = G >> 4, g = G & 15;
    int sw = g ^ (r & 15);
    *(float4*)&As[(r*16 + sw)*8] = *(const float4*)&Arow[(size_t)G*8];
    *(float4*)&Bs[(r*16 + sw)*8] = *(const float4*)&Brow[(size_t)G*8];
  }
  __syncthreads();
  int w = t >> 6, lane = t & 63;
  int rw = (w >> 1)*64, cw = (w & 1)*64;
  int m15 = lane & 15, quad = lane >> 4;
  float4_ acc[4][4] = {};
  #pragma unroll
  for (int kq = 0; kq < 4; kq++) {
    short8 a[4], b[4];
    int g = kq*4 + quad;
    #pragma unroll
    for (int mi = 0; mi < 4; mi++) {
      int r = rw + mi*16 + m15;
      a[mi] = *(const short8*)&As[(r*16 + (g ^ (r & 15)))*8];
    }
    #pragma unroll
    for (int ni = 0; ni < 4; ni++) {
      int r = cw + ni*16 + m15;
      b[ni] = *(const short8*)&Bs[(r*16 + (g ^ (r & 15)))*8];
    }
    #pragma unroll
    for (int mi = 0; mi < 4; mi++)
      #pragma unroll
      for (int ni = 0; ni < 4; ni++)
        acc[mi][ni] = __builtin_amdgcn_mfma_f32_16x16x32_bf16(a[mi], b[ni], acc[mi][ni], 0, 0, 0);
  }
  // epilogue: sim2 = 2*dot (tau=0.5, inputs pre-normalized)
  int i0 = blockIdx.x*128, j0 = blockIdx.y*128;
  float* rowsum = zbuf + z*NS;
  float* colsum = zbuf + 2*NS + z*NS;
  float* diag = dg_all + z*NS;
  float cs[4] = {0,0,0,0};
  #pragma unroll
  for (int mi = 0; mi < 4; mi++) {
    float rs[4] = {0,0,0,0};
    #pragma unroll
    for (int ni = 0; ni < 4; ni++) {
      #pragma unroll
      for (int reg = 0; reg < 4; reg++) {
        float sim2 = acc[mi][ni][reg]*2.0f;
        int gi = i0 + rw + mi*16 + quad*4 + reg;     // C/D: row=(lane>>4)*4+reg
        int gj = j0 + cw + ni*16 + m15;              //      col=lane&15
        if (gi == gj) diag[gi] = sim2;
        float e = __expf(sim2);
        rs[reg] += e; cs[ni] += e;
      }
    }
    #pragma unroll
    for (int reg = 0; reg < 4; reg++) {
      float v = rs[reg];
      v += __shfl_xor(v, 1); v += __shfl_xor(v, 2);
      v += __shfl_xor(v, 4); v += __shfl_xor(v, 8);
      if (m15 == 0) atomicAdd(&rowsum[i0 + rw + mi*16 + quad*4 + reg], v);
    }
  }
  #pragma unroll
  for (int ni = 0; ni < 4; ni++) {
    float v = cs[ni];
    v += __shfl_xor(v, 16); v += __shfl_xor(v, 32);
    if (quad == 0) atomicAdd(&colsum[j0 + cw + ni*16 + m15], v);
  }
}

// single block; writes closs directly to out[BQ]
__global__ void k_loss(const float* __restrict__ zbuf, const float* __restrict__ dg_all,
                       float* __restrict__ out) {
  __shared__ float red[256];
  int t = threadIdx.x;
  float v = 0.f;
  for (int z = 0; z < 2; z++)
    for (int i = t; i < NS; i += 256)
      v += logf(zbuf[z*NS + i]) + logf(zbuf[2*NS + z*NS + i]) - 2.f*dg_all[z*NS + i];
  red[t] = v; __syncthreads();
  for (int off = 128; off > 0; off >>= 1) {
    if (t < off) red[t] += red[t + off];
    __syncthreads();
  }
  if (t == 0) out[BQ] = 0.1f*red[0]/(float)NS;
}

extern "C" void kernel_launch(void* const* d_in, const int* in_sizes, int n_in,
                              void* d_out, int out_size, void* d_ws, size_t ws_size,
                              hipStream_t stream) {
  const float* E_stu  = (const float*)d_in[0];
  const float* E_exer = (const float*)d_in[1];
  const float* E_k    = (const float*)d_in[2];
  const float* W1  = (const float*)d_in[3];
  const float* a1s = (const float*)d_in[4];
  const float* a1d = (const float*)d_in[5];
  const float* W2  = (const float*)d_in[6];
  const float* a2s = (const float*)d_in[7];
  const float* a2d = (const float*)d_in[8];
  const float* pW1 = (const float*)d_in[9];
  const float* pW2 = (const float*)d_in[10];
  const float* pW3 = (const float*)d_in[11];
  const float* pb3 = (const float*)d_in[12];
  const float* kn_r = (const float*)d_in[13];
  const int* stu_ids  = (const int*)d_in[14];
  const int* exer_ids = (const int*)d_in[15];
  const int* k_ids    = (const int*)d_in[16];
  EdgePtrs ep;
  for (int g = 0; g < 3; g++) {
    ep.s_src[g] = (const int*)d_in[17 + g*4];
    ep.s_dst[g] = (const int*)d_in[18 + g*4];
    ep.e_src[g] = (const int*)d_in[19 + g*4];
    ep.e_dst[g] = (const int*)d_in[20 + g*4];
  }
  const int* stu_index  = (const int*)d_in[29];
  const int* exer_index = (const int*)d_in[30];
  float* out = (float*)d_out;   // [0..8191] predictions, [8192] closs

  // ---- workspace carve ----
  char* p = (char*)d_ws;
  auto carve = [&](size_t bytes) -> char* {
    char* r = p; p += (bytes + 255) & ~(size_t)255; return r;
  };
  const size_t NODE_F = (size_t)NNODE*KD;
  float* R1 = (float*)carve((3*NODE_F + 6*NNODE)*4);
  float* h0  = R1;                        // layer-1 h (shared across graphs)
  float* ss0 = R1 + NODE_F;
  float* sd0 = ss0 + NNODE;
  float* h3  = R1;                        // layer-2 h x3 (aliases h0, dead by then... careful)
  float* ss3 = R1 + 3*NODE_F;
  float* sd3 = ss3 + 3*NNODE;
  float* Creg = (float*)carve(3*NODE_F*4);
  float* etmp3 = Creg;                    // layer-1 agg output x3
  float* PD = Creg;                       // aliases etmp3 (dead after layer-2 ngemm)
  float* eoutAll = (float*)carve(3*NODE_F*4);
  int* cnt_all = (int*)carve((size_t)3*NNODE*4);
  int* fill    = (int*)carve((size_t)3*NNODE*4);
  int* rp_all  = (int*)carve((size_t)3*RP*4);
  int* col_all = (int*)carve((size_t)3*NCSR*4);
  float* pWT = (float*)carve((size_t)3*KD*KD*4);
  float* pW1T = pWT, *pW2T = pWT + KD*KD, *pW3T = pWT + 2*KD*KD;
  float* zbuf = (float*)carve((size_t)4*NS*4);     // rs[2][NS], cs[2][NS]
  float* dg_all = (float*)carve((size_t)2*NS*4);
  unsigned short* Z = (unsigned short*)carve((size_t)2*8192*KD*2);  // bf16 Z1|Z2

  // NOTE: h3 aliases h0/R1 start; layer-2 ngemm reads etmp3 and writes h3 (disjoint buffers). ok.

  // ---- zero init (ws poisoned 0xAA every launch) ----
  hipMemsetAsync(cnt_all, 0, (size_t)6*NNODE*4, stream);   // cnt + fill
  hipMemsetAsync(zbuf, 0, (size_t)4*NS*4, stream);

  // ---- CSR build + weight transpose ----
  k_hist<<<dim3(512, 3), 256, 0, stream>>>(ep, cnt_all);
  k_scan<<<3, 1024, 0, stream>>>(cnt_all, rp_all);
  k_scatter<<<dim3(512, 3), 256, 0, stream>>>(ep, rp_all, fill, col_all);
  k_tr<<<dim3(4, 4, 3), dim3(32, 8), 0, stream>>>(pW1, pW2, pW3, pWT);

  // ---- GAT layer 1 (h shared across graphs; embedding gather fused) ----
  k_ngemm<3><<<NNODE/32, 256, 0, stream>>>(nullptr, W1, nullptr, a1s, a1d,
                                           h0, ss0, sd0, NNODE,
                                           E_stu, E_exer, E_k, stu_ids, exer_ids, k_ids);
  k_agg<<<3*NNODE/4, 256, 0, stream>>>(rp_all, col_all, h0, ss0, sd0, etmp3, nullptr);

  // ---- GAT layer 2 ----
  k_ngemm<0><<<3*NNODE/32, 256, 0, stream>>>(etmp3, W2, nullptr, a2s, a2d,
                                             h3, ss3, sd3, 3*NNODE,
                                             nullptr, nullptr, nullptr, nullptr, nullptr, nullptr);
  k_agg<<<3*NNODE/4, 256, 0, stream>>>(rp_all, col_all, h3, ss3, sd3, eoutAll, Z);

  // ---- contrastive loss (bf16 MFMA sim) ----
  k_sim<<<dim3(32, 32, 2), 256, 0, stream>>>(Z, zbuf, dg_all);
  k_loss<<<1, 256, 0, stream>>>(zbuf, dg_all, out);

  // ---- prediction head ----
  k_ngemm<1><<<(2*NS)/32, 256, 0, stream>>>(eoutAll, pW1T, pW2T, pb3, kn_r, PD,
                                            nullptr, nullptr, 2*NS,
                                            nullptr, nullptr, nullptr, nullptr, nullptr, nullptr);
  k_ngemm<2><<<BQ/32, 256, 0, stream>>>(nullptr, pW3T, nullptr, pb3, kn_r, out,
                                        nullptr, nullptr, BQ,
                                        PD, nullptr, nullptr, stu_index, exer_index, nullptr);
}